// Round 1
// baseline (2718.509 us; speedup 1.0000x reference)
//
#include <hip/hip_runtime.h>
#include <cstddef>

// Problem constants
#define B_  4096
#define I_  512
#define L_  128
#define D_  512
#define E_  8
#define H_  512
#define HR_ 256
#define A_  32

__device__ __forceinline__ float sigmoidf_(float x) { return 1.0f / (1.0f + __expf(-x)); }

// Build xcat = concat([x, lang], axis=1): (B, 640) as float4s (160 per row)
__global__ __launch_bounds__(256) void concat_k(const float* __restrict__ x,
                                                const float* __restrict__ lang,
                                                float* __restrict__ xcat) {
    int idx = blockIdx.x * 256 + threadIdx.x;   // over B_*160 float4s
    int b = idx / 160;
    int c = idx - b * 160;
    float4 v;
    if (c < 128) v = ((const float4*)x)[(size_t)b * 128 + c];
    else         v = ((const float4*)lang)[(size_t)b * 32 + (c - 128)];
    ((float4*)xcat)[idx] = v;
}

// C[M,N] = A[M,K] @ B[N,K]^T + bias[n]   (A,B row-major; C row-major stride N)
// MODE 0: C = acc + bias
// MODE 1: C += scale[m*sstride] * (acc + bias)
// MODE 2: C  = scale[m*sstride] * (acc + bias)
// M is implicitly a multiple of 128 (4096). K multiple of 16. N multiple of 4.
template<int MODE>
__global__ __launch_bounds__(256) void gemm128(
    const float* __restrict__ A, const float* __restrict__ Bm,
    const float* __restrict__ bias, float* __restrict__ C,
    int N, int K, const float* __restrict__ scale, int sstride)
{
    __shared__ float As[16][132];
    __shared__ float Bs[16][132];
    const int tid = threadIdx.x;
    const int tx  = tid & 15;
    const int ty  = tid >> 4;
    const int m0  = blockIdx.x * 128;
    const int n0  = blockIdx.y * 128;
    const int lr  = tid >> 2;          // 0..63
    const int lk  = (tid & 3) << 2;    // 0,4,8,12

    float acc[8][8];
#pragma unroll
    for (int i = 0; i < 8; ++i)
#pragma unroll
        for (int j = 0; j < 8; ++j) acc[i][j] = 0.0f;

    const float* Ap0 = A + (size_t)(m0 + lr) * K + lk;
    const float* Ap1 = Ap0 + (size_t)64 * K;
    const int nr0 = n0 + lr, nr1 = n0 + lr + 64;
    const float* Bp0 = Bm + (size_t)nr0 * K + lk;
    const float* Bp1 = Bm + (size_t)nr1 * K + lk;
    const bool bok0 = nr0 < N, bok1 = nr1 < N;

    for (int k0 = 0; k0 < K; k0 += 16) {
        float4 a0 = *(const float4*)(Ap0 + k0);
        float4 a1 = *(const float4*)(Ap1 + k0);
        float4 b0 = bok0 ? *(const float4*)(Bp0 + k0) : make_float4(0.f, 0.f, 0.f, 0.f);
        float4 b1 = bok1 ? *(const float4*)(Bp1 + k0) : make_float4(0.f, 0.f, 0.f, 0.f);
        __syncthreads();
        As[lk+0][lr]    = a0.x; As[lk+1][lr]    = a0.y; As[lk+2][lr]    = a0.z; As[lk+3][lr]    = a0.w;
        As[lk+0][lr+64] = a1.x; As[lk+1][lr+64] = a1.y; As[lk+2][lr+64] = a1.z; As[lk+3][lr+64] = a1.w;
        Bs[lk+0][lr]    = b0.x; Bs[lk+1][lr]    = b0.y; Bs[lk+2][lr]    = b0.z; Bs[lk+3][lr]    = b0.w;
        Bs[lk+0][lr+64] = b1.x; Bs[lk+1][lr+64] = b1.y; Bs[lk+2][lr+64] = b1.z; Bs[lk+3][lr+64] = b1.w;
        __syncthreads();
#pragma unroll
        for (int kk = 0; kk < 16; ++kk) {
            float4 av0 = *(const float4*)&As[kk][ty*8];
            float4 av1 = *(const float4*)&As[kk][ty*8+4];
            float4 bv0 = *(const float4*)&Bs[kk][tx*8];
            float4 bv1 = *(const float4*)&Bs[kk][tx*8+4];
            float a[8]  = {av0.x,av0.y,av0.z,av0.w,av1.x,av1.y,av1.z,av1.w};
            float bb[8] = {bv0.x,bv0.y,bv0.z,bv0.w,bv1.x,bv1.y,bv1.z,bv1.w};
#pragma unroll
            for (int i = 0; i < 8; ++i)
#pragma unroll
                for (int j = 0; j < 8; ++j)
                    acc[i][j] = fmaf(a[i], bb[j], acc[i][j]);
        }
    }

#pragma unroll
    for (int i = 0; i < 8; ++i) {
        const int m = m0 + ty*8 + i;
        float* crow = C + (size_t)m * N;
        float w = 0.0f;
        if (MODE != 0) w = scale[(size_t)m * sstride];
#pragma unroll
        for (int g = 0; g < 2; ++g) {
            const int n = n0 + tx*8 + g*4;
            if (n < N) {
                float4 bv = *(const float4*)(bias + n);
                float4 r;
                r.x = acc[i][g*4+0] + bv.x;
                r.y = acc[i][g*4+1] + bv.y;
                r.z = acc[i][g*4+2] + bv.z;
                r.w = acc[i][g*4+3] + bv.w;
                if (MODE == 1) {
                    float4 old = *(const float4*)(crow + n);
                    r.x = old.x + w * r.x; r.y = old.y + w * r.y;
                    r.z = old.z + w * r.z; r.w = old.w + w * r.w;
                } else if (MODE == 2) {
                    r.x *= w; r.y *= w; r.z *= w; r.w *= w;
                }
                *(float4*)(crow + n) = r;
            }
        }
    }
}

// GRU elementwise: gx, gh are (B, 3*HD) with gate order [r, z, n]; h is (B, HD)
template<int HD>
__global__ __launch_bounds__(256) void gru_k(const float* __restrict__ gx,
                                             const float* __restrict__ gh,
                                             const float* __restrict__ h,
                                             float* __restrict__ hout) {
    constexpr int SH = (HD == 256) ? 8 : 9;
    int idx = blockIdx.x * 256 + threadIdx.x;   // over B_*HD
    int b = idx >> SH;
    int j = idx & (HD - 1);
    const float* gxr = gx + (size_t)b * (3 * HD);
    const float* ghr = gh + (size_t)b * (3 * HD);
    float r = sigmoidf_(gxr[j] + ghr[j]);
    float z = sigmoidf_(gxr[HD + j] + ghr[HD + j]);
    float n = tanhf(gxr[2 * HD + j] + r * ghr[2 * HD + j]);
    hout[idx] = (1.0f - z) * n + z * h[idx];
}

// logits = h_router_new @ W_fc^T + b_fc; weights = softmax(logits) over E=8
// one wave handles 8 rows: lane = rg*8 + e
__global__ __launch_bounds__(256) void fc_softmax_k(const float* __restrict__ hr,
                                                    const float* __restrict__ Wfc,
                                                    const float* __restrict__ bfc,
                                                    float* __restrict__ wts) {
    int lane = threadIdx.x & 63;
    int wave = threadIdx.x >> 6;       // 0..3
    int rg = lane >> 3;                // 0..7
    int e  = lane & 7;
    int b  = blockIdx.x * 32 + wave * 8 + rg;
    const float* h = hr + (size_t)b * HR_;
    const float* w = Wfc + (size_t)e * HR_;
    float acc = 0.0f;
#pragma unroll 4
    for (int k = 0; k < HR_; k += 4) {
        float4 hv = *(const float4*)(h + k);
        float4 wv = *(const float4*)(w + k);
        acc += hv.x * wv.x + hv.y * wv.y + hv.z * wv.z + hv.w * wv.w;
    }
    acc += bfc[e];
    float m = acc;
    for (int off = 4; off; off >>= 1) m = fmaxf(m, __shfl_xor(m, off, 8));
    float ex = __expf(acc - m);
    float s = ex;
    for (int off = 4; off; off >>= 1) s += __shfl_xor(s, off, 8);
    wts[(size_t)b * E_ + e] = ex / s;
}

extern "C" void kernel_launch(void* const* d_in, const int* in_sizes, int n_in,
                              void* d_out, int out_size, void* d_ws, size_t ws_size,
                              hipStream_t stream)
{
    const float* x      = (const float*)d_in[0];
    const float* lang   = (const float*)d_in[1];
    const float* h_r    = (const float*)d_in[2];
    const float* h_e    = (const float*)d_in[3];
    const float* W_in   = (const float*)d_in[4];
    const float* b_in   = (const float*)d_in[5];
    const float* Wih_r  = (const float*)d_in[6];
    const float* Whh_r  = (const float*)d_in[7];
    const float* bih_r  = (const float*)d_in[8];
    const float* bhh_r  = (const float*)d_in[9];
    const float* W_fc   = (const float*)d_in[10];
    const float* b_fc   = (const float*)d_in[11];
    const float* Wih_e  = (const float*)d_in[12];
    const float* Whh_e  = (const float*)d_in[13];
    const float* bih_e  = (const float*)d_in[14];
    const float* bhh_e  = (const float*)d_in[15];
    const float* W_proj = (const float*)d_in[16];
    const float* b_proj = (const float*)d_in[17];
    const float* W_head = (const float*)d_in[18];
    const float* b_head = (const float*)d_in[19];

    float* out_logits = (float*)d_out;                          // B*A
    float* out_hr     = out_logits + (size_t)B_ * A_;           // B*HR
    float* out_he     = out_hr + (size_t)B_ * HR_;              // E*B*H

    // workspace layout (floats), with liveness-based overlap; total 17,334,272 fl = 66.2 MB
    float* ws   = (float*)d_ws;
    float* xcat = ws + 0;          // B*640 = 2,621,440           (dead after in-proj)
    float* xp   = ws + 2621440;    // B*512 = 2,097,152
    float* gxr  = ws + 4718592;    // B*768 = 3,145,728           (dead after router GRU)
    float* ghr  = ws + 7864320;    // B*768 = 3,145,728           (dead after router GRU)
    float* wts  = ws + 11010048;   // B*8   = 32,768
    float* gxe  = ws + 4718592;    // B*1536 = 6,291,456 (reuses gxr+ghr)
    float* ghe  = ws + 11042816;   // B*1536 = 6,291,456
    float* comb = ws + 0;          // B*512 = 2,097,152 (reuses xcat)

    // 1. concat inputs
    concat_k<<<(B_ * 160) / 256, 256, 0, stream>>>(x, lang, xcat);
    // 2. xp = xcat @ W_in^T + b_in          (4096 x 512, K=640)
    gemm128<0><<<dim3(32, D_ / 128), 256, 0, stream>>>(xcat, W_in, b_in, xp, D_, I_ + L_, nullptr, 0);
    // 3. router gate pre-activations
    gemm128<0><<<dim3(32, (3 * HR_) / 128), 256, 0, stream>>>(xp, Wih_r, bih_r, gxr, 3 * HR_, D_, nullptr, 0);
    gemm128<0><<<dim3(32, (3 * HR_) / 128), 256, 0, stream>>>(h_r, Whh_r, bhh_r, ghr, 3 * HR_, HR_, nullptr, 0);
    // 4. router GRU -> h_router_new (output region)
    gru_k<HR_><<<(B_ * HR_) / 256, 256, 0, stream>>>(gxr, ghr, h_r, out_hr);
    // 5. router fc + softmax -> weights
    fc_softmax_k<<<B_ / 32, 256, 0, stream>>>(out_hr, W_fc, b_fc, wts);
    // 6. experts
    for (int e = 0; e < E_; ++e) {
        const float* he_in = h_e + (size_t)e * B_ * H_;
        float* he_out = out_he + (size_t)e * B_ * H_;
        gemm128<0><<<dim3(32, (3 * H_) / 128), 256, 0, stream>>>(
            xp, Wih_e + (size_t)e * 3 * H_ * D_, bih_e + (size_t)e * 3 * H_, gxe, 3 * H_, D_, nullptr, 0);
        gemm128<0><<<dim3(32, (3 * H_) / 128), 256, 0, stream>>>(
            he_in, Whh_e + (size_t)e * 3 * H_ * H_, bhh_e + (size_t)e * 3 * H_, ghe, 3 * H_, H_, nullptr, 0);
        gru_k<H_><<<(B_ * H_) / 256, 256, 0, stream>>>(gxe, ghe, he_in, he_out);
        // combined (+)= weights[:,e] * (h_new @ W_proj[e]^T + b_proj[e])
        if (e == 0)
            gemm128<2><<<dim3(32, D_ / 128), 256, 0, stream>>>(
                he_out, W_proj, b_proj, comb, D_, H_, wts + 0, E_);
        else
            gemm128<1><<<dim3(32, D_ / 128), 256, 0, stream>>>(
                he_out, W_proj + (size_t)e * D_ * H_, b_proj + (size_t)e * D_, comb, D_, H_, wts + e, E_);
    }
    // 7. logits = combined @ W_head^T + b_head   (4096 x 32)
    gemm128<0><<<dim3(32, 1), 256, 0, stream>>>(comb, W_head, b_head, out_logits, A_, D_, nullptr, 0);
}

// Round 4
// 1119.300 us; speedup vs baseline: 2.4288x; 2.4288x over previous
//
#include <hip/hip_runtime.h>
#include <cstddef>
#include <cstdint>

// Problem constants
#define B_  4096
#define I_  512
#define L_  128
#define D_  512
#define E_  8
#define H_  512
#define HR_ 256
#define A_  32

typedef __attribute__((ext_vector_type(8))) __bf16 bf16x8;
typedef __attribute__((ext_vector_type(4))) __bf16 bf16x4;
typedef __attribute__((ext_vector_type(4))) float floatx4;

__device__ __forceinline__ float sigmoidf_(float x) { return 1.0f / (1.0f + __expf(-x)); }

__device__ __forceinline__ void load_lds16(const void* g, void* l) {
    __builtin_amdgcn_global_load_lds((__attribute__((address_space(1))) void*)g,
                                     (__attribute__((address_space(3))) void*)l, 16, 0, 0);
}

struct HiLo { __bf16 h, l; };
__device__ __forceinline__ HiLo hi_lo(float v) {
    HiLo r;
    r.h = (__bf16)v;
    r.l = (__bf16)(v - (float)r.h);
    return r;
}
__device__ __forceinline__ void split4(float4 v, bf16x4& hi, bf16x4& lo) {
    HiLo a = hi_lo(v.x), b = hi_lo(v.y), c = hi_lo(v.z), d = hi_lo(v.w);
    hi = (bf16x4){a.h, b.h, c.h, d.h};
    lo = (bf16x4){a.l, b.l, c.l, d.l};
}

// ---------------- conversion kernels ----------------
__global__ __launch_bounds__(256) void f2b_k(const float* __restrict__ src,
                                             __bf16* __restrict__ dst, int n4) {
    int i = blockIdx.x * 256 + threadIdx.x;
    if (i < n4) {
        float4 v = ((const float4*)src)[i];
        bf16x4 o = { (__bf16)v.x, (__bf16)v.y, (__bf16)v.z, (__bf16)v.w };
        *(bf16x4*)(dst + (size_t)i * 4) = o;
    }
}

// weight split-cat: W (N,K) fp32 -> out (N,3K) bf16 = [W_hi | W_hi | W_lo] per row
__global__ __launch_bounds__(256) void wcat_k(const float* __restrict__ W,
                                              __bf16* __restrict__ out,
                                              int K4, int n4tot) {
    int i4 = blockIdx.x * 256 + threadIdx.x;
    if (i4 >= n4tot) return;
    int row = i4 / K4;
    int c4  = i4 - row * K4;
    const int K = K4 * 4;
    float4 v = ((const float4*)W)[i4];
    bf16x4 hi, lo;
    split4(v, hi, lo);
    __bf16* dst = out + (size_t)row * 3 * K + c4 * 4;
    *(bf16x4*)(dst)         = hi;
    *(bf16x4*)(dst + K)     = hi;
    *(bf16x4*)(dst + 2 * K) = lo;
}

// concat + split-cat: [x (B,512) | lang (B,128)] -> xcat_cat (B,1920) = [hi | lo | hi]
__global__ __launch_bounds__(256) void concat_cat_k(const float* __restrict__ x,
                                                    const float* __restrict__ lang,
                                                    __bf16* __restrict__ out) {
    int idx = blockIdx.x * 256 + threadIdx.x;   // over B_*160 float4 groups
    int b = idx / 160;
    int c = idx - b * 160;
    float4 v;
    if (c < 128) v = ((const float4*)x)[(size_t)b * 128 + c];
    else         v = ((const float4*)lang)[(size_t)b * 32 + (c - 128)];
    bf16x4 hi, lo;
    split4(v, hi, lo);
    __bf16* dst = out + (size_t)b * 1920 + c * 4;
    *(bf16x4*)(dst)        = hi;
    *(bf16x4*)(dst + 640)  = lo;
    *(bf16x4*)(dst + 1280) = hi;
}

// xp fp32 (B,512) -> xp_cat (B,1536) = [hi | lo | hi]
__global__ __launch_bounds__(256) void split2cat_k(const float* __restrict__ src,
                                                   __bf16* __restrict__ out) {
    int i4 = blockIdx.x * 256 + threadIdx.x;    // over B_*128
    int b = i4 >> 7;
    int c4 = i4 & 127;
    float4 v = ((const float4*)src)[i4];
    bf16x4 hi, lo;
    split4(v, hi, lo);
    __bf16* dst = out + (size_t)b * 1536 + c4 * 4;
    *(bf16x4*)(dst)         = hi;
    *(bf16x4*)(dst + 512)   = lo;
    *(bf16x4*)(dst + 1024)  = hi;
}

// ---------------- MFMA GEMM (m97-style) ----------------
// C[m,n] (+=) A[m,K] @ Bw[n,K]^T + bias[n], batched over blockIdx.z.
// MODE 0: C fp32 = acc+bias
// MODE 1: C bf16 = acc+bias
// MODE 2: C fp32 = scale[m*sstride+z*szBatch] * (acc+bias)
// MODE 3: C fp32 += scale[m*sstride+z*szBatch] * (acc+bias)
template<int MODE>
__global__ __launch_bounds__(256) void mgemm(
    const __bf16* __restrict__ A, long long aBatch,
    const __bf16* __restrict__ Bw, long long bBatch,
    const float* __restrict__ bias, long long biasBatch,
    void* __restrict__ Cv, long long cBatch,
    int N, int K,
    const float* __restrict__ scale, int sstride, int szBatch)
{
    __shared__ __align__(16) __bf16 As[128 * 32];
    __shared__ __align__(16) __bf16 Bs[128 * 32];

    const int tid  = threadIdx.x;
    const int w    = tid >> 6;
    const int lane = tid & 63;
    const int m0 = blockIdx.x * 128;
    const int n0 = blockIdx.y * 128;
    const int z  = blockIdx.z;

    const int lrow = lane >> 2;
    const int lseg = lane & 3;
    const __bf16* Ag0 = A + (size_t)z * aBatch + (size_t)(m0 + w * 32 + lrow) * K + lseg * 8;
    const __bf16* Ag1 = Ag0 + (size_t)16 * K;
    const __bf16* Bg0 = Bw + (size_t)z * bBatch + (size_t)(n0 + w * 32 + lrow) * K + lseg * 8;
    const __bf16* Bg1 = Bg0 + (size_t)16 * K;
    __bf16* Al0 = As + (w * 32) * 32;
    __bf16* Al1 = Al0 + 16 * 32;
    __bf16* Bl0 = Bs + (w * 32) * 32;
    __bf16* Bl1 = Bl0 + 16 * 32;

    const int wm = w & 1, wn = w >> 1;
    const int lr16 = lane & 15;
    const int lq   = lane >> 4;
    const __bf16* Af = As + (wm * 64 + lr16) * 32 + lq * 8;
    const __bf16* Bf = Bs + (wn * 64 + lr16) * 32 + lq * 8;

    floatx4 acc[4][4];
#pragma unroll
    for (int i = 0; i < 4; ++i)
#pragma unroll
        for (int j = 0; j < 4; ++j) acc[i][j] = (floatx4){0.f, 0.f, 0.f, 0.f};

    for (int k0 = 0; k0 < K; k0 += 32) {
        __syncthreads();
        load_lds16(Ag0 + k0, Al0);
        load_lds16(Ag1 + k0, Al1);
        load_lds16(Bg0 + k0, Bl0);
        load_lds16(Bg1 + k0, Bl1);
        __syncthreads();

        bf16x8 af[4], bfr[4];
#pragma unroll
        for (int t = 0; t < 4; ++t) {
            af[t]  = *(const bf16x8*)(Af + t * 16 * 32);
            bfr[t] = *(const bf16x8*)(Bf + t * 16 * 32);
        }
#pragma unroll
        for (int tm = 0; tm < 4; ++tm)
#pragma unroll
            for (int tn = 0; tn < 4; ++tn)
                acc[tm][tn] = __builtin_amdgcn_mfma_f32_16x16x32_bf16(af[tm], bfr[tn], acc[tm][tn], 0, 0, 0);
    }

    const float* biasz = bias + (size_t)z * biasBatch;
    const int sz = z * szBatch;
#pragma unroll
    for (int tm = 0; tm < 4; ++tm) {
        const int mbase = m0 + wm * 64 + tm * 16 + lq * 4;
#pragma unroll
        for (int r = 0; r < 4; ++r) {
            const int m = mbase + r;
            float wsc = 0.f;
            if (MODE >= 2) wsc = scale[(size_t)m * sstride + sz];
#pragma unroll
            for (int tn = 0; tn < 4; ++tn) {
                const int n = n0 + wn * 64 + tn * 16 + lr16;
                float v = acc[tm][tn][r] + biasz[n];
                const size_t ci = (size_t)z * cBatch + (size_t)m * N + n;
                if (MODE == 0)      ((float*)Cv)[ci] = v;
                else if (MODE == 1) ((__bf16*)Cv)[ci] = (__bf16)v;
                else if (MODE == 2) ((float*)Cv)[ci] = wsc * v;
                else                ((float*)Cv)[ci] += wsc * v;
            }
        }
    }
}

// ---------------- GRU elementwise ----------------
template<int HD, bool WB>
__global__ __launch_bounds__(256) void gru_k(const float* __restrict__ gx,
                                             const float* __restrict__ gh,
                                             const float* __restrict__ h,
                                             float* __restrict__ hout,
                                             __bf16* __restrict__ houtb) {
    size_t i4  = (size_t)blockIdx.x * 256 + threadIdx.x;
    size_t idx = i4 * 4;
    size_t bg = idx / HD;
    int    j  = (int)(idx % HD);
    const float* gxr = gx + bg * (3 * HD) + j;
    const float* ghr = gh + bg * (3 * HD) + j;
    float4 xr = *(const float4*)(gxr);
    float4 hr = *(const float4*)(ghr);
    float4 xz = *(const float4*)(gxr + HD);
    float4 hz = *(const float4*)(ghr + HD);
    float4 xn = *(const float4*)(gxr + 2 * HD);
    float4 hn = *(const float4*)(ghr + 2 * HD);
    float4 hv = *(const float4*)(h + idx);
    float4 o;
    {
        float r = sigmoidf_(xr.x + hr.x), zz = sigmoidf_(xz.x + hz.x);
        float n = tanhf(xn.x + r * hn.x); o.x = (1.f - zz) * n + zz * hv.x;
    }
    {
        float r = sigmoidf_(xr.y + hr.y), zz = sigmoidf_(xz.y + hz.y);
        float n = tanhf(xn.y + r * hn.y); o.y = (1.f - zz) * n + zz * hv.y;
    }
    {
        float r = sigmoidf_(xr.z + hr.z), zz = sigmoidf_(xz.z + hz.z);
        float n = tanhf(xn.z + r * hn.z); o.z = (1.f - zz) * n + zz * hv.z;
    }
    {
        float r = sigmoidf_(xr.w + hr.w), zz = sigmoidf_(xz.w + hz.w);
        float n = tanhf(xn.w + r * hn.w); o.w = (1.f - zz) * n + zz * hv.w;
    }
    *(float4*)(hout + idx) = o;
    if (WB) {
        bf16x4 ob = { (__bf16)o.x, (__bf16)o.y, (__bf16)o.z, (__bf16)o.w };
        *(bf16x4*)(houtb + idx) = ob;
    }
}

// ---------------- router fc + softmax ----------------
__global__ __launch_bounds__(256) void fc_softmax_k(const float* __restrict__ hr,
                                                    const float* __restrict__ Wfc,
                                                    const float* __restrict__ bfc,
                                                    float* __restrict__ wts) {
    int lane = threadIdx.x & 63;
    int wave = threadIdx.x >> 6;
    int rg = lane >> 3;
    int e  = lane & 7;
    int b  = blockIdx.x * 32 + wave * 8 + rg;
    const float* h = hr + (size_t)b * HR_;
    const float* w = Wfc + (size_t)e * HR_;
    float acc = 0.0f;
#pragma unroll 4
    for (int k = 0; k < HR_; k += 4) {
        float4 hv = *(const float4*)(h + k);
        float4 wv = *(const float4*)(w + k);
        acc += hv.x * wv.x + hv.y * wv.y + hv.z * wv.z + hv.w * wv.w;
    }
    acc += bfc[e];
    float m = acc;
    for (int off = 4; off; off >>= 1) m = fmaxf(m, __shfl_xor(m, off, 8));
    float ex = __expf(acc - m);
    float s = ex;
    for (int off = 4; off; off >>= 1) s += __shfl_xor(s, off, 8);
    wts[(size_t)b * E_ + e] = ex / s;
}

// ---------------- reduce 8 expert planes -> comb fp32 ----------------
__global__ __launch_bounds__(256) void reduce8_k(const float* __restrict__ P,
                                                 float* __restrict__ comb) {
    size_t i = (size_t)blockIdx.x * 256 + threadIdx.x;
    const size_t ps = (size_t)B_ * D_ / 4;
    float4 s = ((const float4*)P)[i];
#pragma unroll
    for (int e = 1; e < E_; ++e) {
        float4 v = ((const float4*)P)[i + (size_t)e * ps];
        s.x += v.x; s.y += v.y; s.z += v.z; s.w += v.w;
    }
    ((float4*)comb)[i] = s;
}

// ---------------- head ----------------
__global__ __launch_bounds__(256) void head_k(const float* __restrict__ comb,
                                              const float* __restrict__ Wh,
                                              const float* __restrict__ bh,
                                              float* __restrict__ out) {
    __shared__ float hs[8][512];
    int b0 = blockIdx.x * 8;
    for (int i = threadIdx.x; i < 8 * 128; i += 256) {
        int rr = i >> 7, cc = i & 127;
        ((float4*)hs[rr])[cc] = ((const float4*)(comb + (size_t)(b0 + rr) * 512))[cc];
    }
    __syncthreads();
    int r = threadIdx.x >> 5, c = threadIdx.x & 31;
    const float* wrow = Wh + (size_t)c * 512;
    float acc = 0.f;
    for (int k = 0; k < 512; k += 4) {
        float4 wv = *(const float4*)(wrow + k);
        float4 hv = *(const float4*)(&hs[r][k]);
        acc += hv.x * wv.x + hv.y * wv.y + hv.z * wv.z + hv.w * wv.w;
    }
    out[(size_t)(b0 + r) * 32 + c] = acc + bh[c];
}

// ---------------- launcher ----------------
extern "C" void kernel_launch(void* const* d_in, const int* in_sizes, int n_in,
                              void* d_out, int out_size, void* d_ws, size_t ws_size,
                              hipStream_t stream)
{
    const float* x      = (const float*)d_in[0];
    const float* lang   = (const float*)d_in[1];
    const float* h_r    = (const float*)d_in[2];
    const float* h_e    = (const float*)d_in[3];
    const float* W_in   = (const float*)d_in[4];
    const float* b_in   = (const float*)d_in[5];
    const float* Wih_r  = (const float*)d_in[6];
    const float* Whh_r  = (const float*)d_in[7];
    const float* bih_r  = (const float*)d_in[8];
    const float* bhh_r  = (const float*)d_in[9];
    const float* W_fc   = (const float*)d_in[10];
    const float* b_fc   = (const float*)d_in[11];
    const float* Wih_e  = (const float*)d_in[12];
    const float* Whh_e  = (const float*)d_in[13];
    const float* bih_e  = (const float*)d_in[14];
    const float* bhh_e  = (const float*)d_in[15];
    const float* W_proj = (const float*)d_in[16];
    const float* b_proj = (const float*)d_in[17];
    const float* W_head = (const float*)d_in[18];
    const float* b_head = (const float*)d_in[19];

    float* out_logits = (float*)d_out;                 // B*A
    float* out_hr     = out_logits + (size_t)B_ * A_;  // B*HR
    float* out_he     = out_hr + (size_t)B_ * HR_;     // E*B*H

    char* wsb = (char*)d_ws;
    size_t off = 0;
    auto alloc = [&](size_t bytes) -> char* {
        char* p = wsb + off;
        off = (off + bytes + 255) & ~(size_t)255;
        return p;
    };

    // persistent: split-cat / bf16 weights
    __bf16* W_in_cat  = (__bf16*)alloc((size_t)512 * 1920 * 2);       // [hi|hi|lo]
    __bf16* Wih_r_cat = (__bf16*)alloc((size_t)768 * 1536 * 2);
    __bf16* Wih_e_cat = (__bf16*)alloc((size_t)12288 * 1536 * 2);     // 8 experts stacked
    __bf16* Whh_r_b   = (__bf16*)alloc((size_t)768 * 256 * 2);
    __bf16* Whh_e_b   = (__bf16*)alloc((size_t)8 * 1536 * 512 * 2);
    __bf16* W_proj_b  = (__bf16*)alloc((size_t)8 * 512 * 512 * 2);
    __bf16* xp_cat    = (__bf16*)alloc((size_t)B_ * 1536 * 2);
    __bf16* hr_b      = (__bf16*)alloc((size_t)B_ * HR_ * 2);
    float*  wts       = (float*)alloc((size_t)B_ * E_ * 4);
    float*  comb      = (float*)alloc((size_t)B_ * D_ * 4);

    const size_t heN   = (size_t)E_ * B_ * H_;       // 16,777,216
    const size_t gateN = (size_t)E_ * B_ * 3 * H_;   // 50,331,648
    const size_t tierA_need = off + heN * 2 * 2 + gateN * 4 * 2 + (1 << 20);
    const bool tierA = (ws_size >= tierA_need);

    // weight prep
    wcat_k<<<(512 * 160 + 255) / 256, 256, 0, stream>>>(W_in, W_in_cat, 160, 512 * 160);
    wcat_k<<<(768 * 128 + 255) / 256, 256, 0, stream>>>(Wih_r, Wih_r_cat, 128, 768 * 128);
    wcat_k<<<(12288 * 128 + 255) / 256, 256, 0, stream>>>(Wih_e, Wih_e_cat, 128, 12288 * 128);
    f2b_k<<<(196608 / 4 + 255) / 256, 256, 0, stream>>>(Whh_r, Whh_r_b, 196608 / 4);
    f2b_k<<<(6291456 / 4 + 255) / 256, 256, 0, stream>>>(Whh_e, Whh_e_b, 6291456 / 4);
    f2b_k<<<(2097152 / 4 + 255) / 256, 256, 0, stream>>>(W_proj, W_proj_b, 2097152 / 4);
    f2b_k<<<((B_ * HR_) / 4 + 255) / 256, 256, 0, stream>>>(h_r, hr_b, (B_ * HR_) / 4);

    if (tierA) {
        __bf16* he_b    = (__bf16*)alloc(heN * 2);
        __bf16* henew_b = (__bf16*)alloc(heN * 2);
        float*  gxe     = (float*)alloc(gateN * 4);
        float*  ghe     = (float*)alloc(gateN * 4);
        // overlapped scratch (dead before gxe/ghe written):
        __bf16* xcat_cat = (__bf16*)gxe;            // B*1920 bf16 = 15.7 MB
        float*  xp       = (float*)ghe;             // B*512 fp32 = 8.4 MB
        float*  gxr = gxe;                          // router gates (dead before expert gates)
        float*  ghr = ghe;
        float*  P   = gxe;                          // proj planes (after GRU, gates dead)

        // input proj (split-accurate): xp = [xcat_hi|xcat_lo|xcat_hi] @ W_in_cat^T + b_in
        concat_cat_k<<<(B_ * 160) / 256, 256, 0, stream>>>(x, lang, xcat_cat);
        mgemm<0><<<dim3(32, 4, 1), 256, 0, stream>>>(xcat_cat, 0, W_in_cat, 0, b_in, 0,
                                                     xp, 0, D_, 1920, nullptr, 0, 0);
        split2cat_k<<<(B_ * 128) / 256, 256, 0, stream>>>(xp, xp_cat);

        // router (gx split-accurate; gh bf16 — h_router is zeros so exact anyway)
        mgemm<0><<<dim3(32, 6, 1), 256, 0, stream>>>(xp_cat, 0, Wih_r_cat, 0, bih_r, 0,
                                                     gxr, 0, 3 * HR_, 1536, nullptr, 0, 0);
        mgemm<0><<<dim3(32, 6, 1), 256, 0, stream>>>(hr_b, 0, Whh_r_b, 0, bhh_r, 0,
                                                     ghr, 0, 3 * HR_, HR_, nullptr, 0, 0);
        gru_k<HR_, false><<<(B_ * HR_) / 1024, 256, 0, stream>>>(gxr, ghr, h_r, out_hr, nullptr);
        fc_softmax_k<<<B_ / 32, 256, 0, stream>>>(out_hr, W_fc, b_fc, wts);

        // experts, batched over z; gx split-accurate
        f2b_k<<<(int)(heN / 4 / 256), 256, 0, stream>>>(h_e, he_b, (int)(heN / 4));
        mgemm<0><<<dim3(32, 12, 8), 256, 0, stream>>>(
            xp_cat, 0, Wih_e_cat, (long long)1536 * 1536, bih_e, 3 * H_,
            gxe, (long long)B_ * 3 * H_, 3 * H_, 1536, nullptr, 0, 0);
        mgemm<0><<<dim3(32, 12, 8), 256, 0, stream>>>(
            he_b, (long long)B_ * H_, Whh_e_b, (long long)3 * H_ * H_, bhh_e, 3 * H_,
            ghe, (long long)B_ * 3 * H_, 3 * H_, H_, nullptr, 0, 0);
        gru_k<H_, true><<<(int)(heN / 1024), 256, 0, stream>>>(gxe, ghe, h_e, out_he, henew_b);

        mgemm<2><<<dim3(32, 4, 8), 256, 0, stream>>>(
            henew_b, (long long)B_ * H_, W_proj_b, (long long)D_ * H_, b_proj, D_,
            P, (long long)B_ * D_, D_, H_, wts, E_, 1);
        reduce8_k<<<(B_ * D_ / 4) / 256, 256, 0, stream>>>(P, comb);
    } else {
        // tier B: per-expert serial loop (~145 MB)
        __bf16* heb_s   = (__bf16*)alloc((size_t)B_ * H_ * 2);
        __bf16* henew_s = (__bf16*)alloc((size_t)B_ * H_ * 2);
        float*  gxe = (float*)alloc((size_t)B_ * 3 * H_ * 4);   // 25.2 MB
        float*  ghe = (float*)alloc((size_t)B_ * 3 * H_ * 4);
        __bf16* xcat_cat = (__bf16*)gxe;     // 15.7 MB, dead after in-proj
        float*  xp       = (float*)ghe;      // 8.4 MB, dead after split
        float*  gxr = gxe;
        float*  ghr = ghe;

        concat_cat_k<<<(B_ * 160) / 256, 256, 0, stream>>>(x, lang, xcat_cat);
        mgemm<0><<<dim3(32, 4, 1), 256, 0, stream>>>(xcat_cat, 0, W_in_cat, 0, b_in, 0,
                                                     xp, 0, D_, 1920, nullptr, 0, 0);
        split2cat_k<<<(B_ * 128) / 256, 256, 0, stream>>>(xp, xp_cat);

        mgemm<0><<<dim3(32, 6, 1), 256, 0, stream>>>(xp_cat, 0, Wih_r_cat, 0, bih_r, 0,
                                                     gxr, 0, 3 * HR_, 1536, nullptr, 0, 0);
        mgemm<0><<<dim3(32, 6, 1), 256, 0, stream>>>(hr_b, 0, Whh_r_b, 0, bhh_r, 0,
                                                     ghr, 0, 3 * HR_, HR_, nullptr, 0, 0);
        gru_k<HR_, false><<<(B_ * HR_) / 1024, 256, 0, stream>>>(gxr, ghr, h_r, out_hr, nullptr);
        fc_softmax_k<<<B_ / 32, 256, 0, stream>>>(out_hr, W_fc, b_fc, wts);

        for (int e = 0; e < E_; ++e) {
            const float* hep = h_e + (size_t)e * B_ * H_;
            float* heo = out_he + (size_t)e * B_ * H_;
            f2b_k<<<(B_ * H_ / 4) / 256, 256, 0, stream>>>(hep, heb_s, B_ * H_ / 4);
            mgemm<0><<<dim3(32, 12, 1), 256, 0, stream>>>(
                xp_cat, 0, Wih_e_cat + (size_t)e * 1536 * 1536, 0, bih_e + (size_t)e * 3 * H_, 0,
                gxe, 0, 3 * H_, 1536, nullptr, 0, 0);
            mgemm<0><<<dim3(32, 12, 1), 256, 0, stream>>>(
                heb_s, 0, Whh_e_b + (size_t)e * 3 * H_ * H_, 0, bhh_e + (size_t)e * 3 * H_, 0,
                ghe, 0, 3 * H_, H_, nullptr, 0, 0);
            gru_k<H_, true><<<(B_ * H_) / 1024, 256, 0, stream>>>(gxe, ghe, hep, heo, henew_s);
            if (e == 0)
                mgemm<2><<<dim3(32, 4, 1), 256, 0, stream>>>(
                    henew_s, 0, W_proj_b, 0, b_proj, 0,
                    comb, 0, D_, H_, wts + e, E_, 0);
            else
                mgemm<3><<<dim3(32, 4, 1), 256, 0, stream>>>(
                    henew_s, 0, W_proj_b + (size_t)e * D_ * H_, 0, b_proj + (size_t)e * D_, 0,
                    comb, 0, D_, H_, wts + e, E_, 0);
        }
    }

    head_k<<<B_ / 8, 256, 0, stream>>>(comb, W_head, b_head, out_logits);
}

// Round 5
// 878.938 us; speedup vs baseline: 3.0929x; 1.2735x over previous
//
#include <hip/hip_runtime.h>
#include <cstddef>
#include <cstdint>

// Problem constants
#define B_  4096
#define I_  512
#define L_  128
#define D_  512
#define E_  8
#define H_  512
#define HR_ 256
#define A_  32

typedef __attribute__((ext_vector_type(8))) __bf16 bf16x8;
typedef __attribute__((ext_vector_type(4))) __bf16 bf16x4;
typedef __attribute__((ext_vector_type(4))) float floatx4;

__device__ __forceinline__ float sigmoidf_(float x) { return 1.0f / (1.0f + __expf(-x)); }

__device__ __forceinline__ void load_lds16(const void* g, void* l) {
    __builtin_amdgcn_global_load_lds((__attribute__((address_space(1))) void*)g,
                                     (__attribute__((address_space(3))) void*)l, 16, 0, 0);
}

struct HiLo { __bf16 h, l; };
__device__ __forceinline__ HiLo hi_lo(float v) {
    HiLo r;
    r.h = (__bf16)v;
    r.l = (__bf16)(v - (float)r.h);
    return r;
}
__device__ __forceinline__ void split4(float4 v, bf16x4& hi, bf16x4& lo) {
    HiLo a = hi_lo(v.x), b = hi_lo(v.y), c = hi_lo(v.z), d = hi_lo(v.w);
    hi = (bf16x4){a.h, b.h, c.h, d.h};
    lo = (bf16x4){a.l, b.l, c.l, d.l};
}

// ---------------- conversion kernels ----------------
__global__ __launch_bounds__(256) void f2b_k(const float* __restrict__ src,
                                             __bf16* __restrict__ dst, int n4) {
    int i = blockIdx.x * 256 + threadIdx.x;
    if (i < n4) {
        float4 v = ((const float4*)src)[i];
        bf16x4 o = { (__bf16)v.x, (__bf16)v.y, (__bf16)v.z, (__bf16)v.w };
        *(bf16x4*)(dst + (size_t)i * 4) = o;
    }
}

// W (N,K) fp32 -> out (N,2K) bf16 = [W_hi | W_lo] per row
__global__ __launch_bounds__(256) void wcat2_k(const float* __restrict__ W,
                                               __bf16* __restrict__ out,
                                               int K4, int n4tot) {
    int i4 = blockIdx.x * 256 + threadIdx.x;
    if (i4 >= n4tot) return;
    int row = i4 / K4;
    int c4  = i4 - row * K4;
    const int K = K4 * 4;
    float4 v = ((const float4*)W)[i4];
    bf16x4 hi, lo;
    split4(v, hi, lo);
    __bf16* dst = out + (size_t)row * 2 * K + c4 * 4;
    *(bf16x4*)(dst)     = hi;
    *(bf16x4*)(dst + K) = lo;
}

// [x (B,512) | lang (B,128)] -> xcat (B,1920) = [hi | hi | lo]
__global__ __launch_bounds__(256) void concat_cat_k(const float* __restrict__ x,
                                                    const float* __restrict__ lang,
                                                    __bf16* __restrict__ out) {
    int idx = blockIdx.x * 256 + threadIdx.x;   // over B_*160 float4 groups
    int b = idx / 160;
    int c = idx - b * 160;
    float4 v;
    if (c < 128) v = ((const float4*)x)[(size_t)b * 128 + c];
    else         v = ((const float4*)lang)[(size_t)b * 32 + (c - 128)];
    bf16x4 hi, lo;
    split4(v, hi, lo);
    __bf16* dst = out + (size_t)b * 1920 + c * 4;
    *(bf16x4*)(dst)        = hi;
    *(bf16x4*)(dst + 640)  = hi;
    *(bf16x4*)(dst + 1280) = lo;
}

// xp fp32 (B,512) -> xp_cat (B,1536) = [hi | hi | lo]
__global__ __launch_bounds__(256) void split2cat_k(const float* __restrict__ src,
                                                   __bf16* __restrict__ out) {
    int i4 = blockIdx.x * 256 + threadIdx.x;    // over B_*128
    int b = i4 >> 7;
    int c4 = i4 & 127;
    float4 v = ((const float4*)src)[i4];
    bf16x4 hi, lo;
    split4(v, hi, lo);
    __bf16* dst = out + (size_t)b * 1536 + c4 * 4;
    *(bf16x4*)(dst)         = hi;
    *(bf16x4*)(dst + 512)   = hi;
    *(bf16x4*)(dst + 1024)  = lo;
}

// h_e chunk convert: (E, B, H) fp32 rows [r0, r0+1024) -> (E, 1024, H) bf16
__global__ __launch_bounds__(256) void f2bhe_k(const float* __restrict__ he,
                                               __bf16* __restrict__ dst, int r0) {
    int i4 = blockIdx.x * 256 + threadIdx.x;    // over 8*1024*128
    int e   = i4 >> 17;
    int rem = i4 & 131071;
    int row = rem >> 7;
    int c4  = rem & 127;
    float4 v = ((const float4*)he)[(size_t)e * (B_ * 128) + (size_t)(r0 + row) * 128 + c4];
    bf16x4 o = { (__bf16)v.x, (__bf16)v.y, (__bf16)v.z, (__bf16)v.w };
    *(bf16x4*)(dst + (size_t)i4 * 4) = o;
}

// ---------------- MFMA GEMM ----------------
// C[m,n] = f(A[m,K] @ Bw[n,:]^T + bias[n]) batched over blockIdx.z.
// B k-index wraps at kWrap (k_eff = k<kWrap ? k : k-kWrap); B row stride = bRS.
// MODE 0: C fp32 = acc+bias
// MODE 2: C fp32 = scale[m*sstride+z*szBatch] * (acc+bias)
template<int MODE>
__global__ __launch_bounds__(256) void mgemm(
    const __bf16* __restrict__ A, long long aBatch,
    const __bf16* __restrict__ Bw, long long bBatch, int bRS, int kWrap,
    const float* __restrict__ bias, long long biasBatch,
    float* __restrict__ Cv, long long cBatch,
    int N, int K,
    const float* __restrict__ scale, int sstride, int szBatch)
{
    __shared__ __align__(16) __bf16 As[128 * 32];
    __shared__ __align__(16) __bf16 Bs[128 * 32];

    const int tid  = threadIdx.x;
    const int w    = tid >> 6;
    const int lane = tid & 63;
    const int m0 = blockIdx.x * 128;
    const int n0 = blockIdx.y * 128;
    const int z  = blockIdx.z;

    const int lrow = lane >> 2;
    const int lseg = lane & 3;
    const __bf16* Ag0 = A + (size_t)z * aBatch + (size_t)(m0 + w * 32 + lrow) * K + lseg * 8;
    const __bf16* Ag1 = Ag0 + (size_t)16 * K;
    const __bf16* Bg0 = Bw + (size_t)z * bBatch + (size_t)(n0 + w * 32 + lrow) * bRS + lseg * 8;
    const __bf16* Bg1 = Bg0 + (size_t)16 * bRS;
    __bf16* Al0 = As + (w * 32) * 32;
    __bf16* Al1 = Al0 + 16 * 32;
    __bf16* Bl0 = Bs + (w * 32) * 32;
    __bf16* Bl1 = Bl0 + 16 * 32;

    const int wm = w & 1, wn = w >> 1;
    const int lr16 = lane & 15;
    const int lq   = lane >> 4;
    const __bf16* Af = As + (wm * 64 + lr16) * 32 + lq * 8;
    const __bf16* Bf = Bs + (wn * 64 + lr16) * 32 + lq * 8;

    floatx4 acc[4][4];
#pragma unroll
    for (int i = 0; i < 4; ++i)
#pragma unroll
        for (int j = 0; j < 4; ++j) acc[i][j] = (floatx4){0.f, 0.f, 0.f, 0.f};

    for (int k0 = 0; k0 < K; k0 += 32) {
        const int kb = (k0 < kWrap) ? k0 : (k0 - kWrap);
        __syncthreads();
        load_lds16(Ag0 + k0, Al0);
        load_lds16(Ag1 + k0, Al1);
        load_lds16(Bg0 + kb, Bl0);
        load_lds16(Bg1 + kb, Bl1);
        __syncthreads();

        bf16x8 af[4], bfr[4];
#pragma unroll
        for (int t = 0; t < 4; ++t) {
            af[t]  = *(const bf16x8*)(Af + t * 16 * 32);
            bfr[t] = *(const bf16x8*)(Bf + t * 16 * 32);
        }
#pragma unroll
        for (int tm = 0; tm < 4; ++tm)
#pragma unroll
            for (int tn = 0; tn < 4; ++tn)
                acc[tm][tn] = __builtin_amdgcn_mfma_f32_16x16x32_bf16(af[tm], bfr[tn], acc[tm][tn], 0, 0, 0);
    }

    const float* biasz = bias + (size_t)z * biasBatch;
    const int sz = z * szBatch;
#pragma unroll
    for (int tm = 0; tm < 4; ++tm) {
        const int mbase = m0 + wm * 64 + tm * 16 + lq * 4;
#pragma unroll
        for (int r = 0; r < 4; ++r) {
            const int m = mbase + r;
            float wsc = 0.f;
            if (MODE == 2) wsc = scale[(size_t)m * sstride + sz];
#pragma unroll
            for (int tn = 0; tn < 4; ++tn) {
                const int n = n0 + wn * 64 + tn * 16 + lr16;
                float v = acc[tm][tn][r] + biasz[n];
                const size_t ci = (size_t)z * cBatch + (size_t)m * N + n;
                if (MODE == 0) Cv[ci] = v;
                else           Cv[ci] = wsc * v;
            }
        }
    }
}

// ---------------- fused gh-GEMM + GRU ----------------
// Per block: 128 rows x 64 h-cols x 3 gates of gh = hprev_b @ Whh^T (+bhh),
// then GRU with gx (fp32, bias included) and hprev (fp32); writes hout fp32
// (+ optional hnew bf16). Batched over blockIdx.z.
template<int HD, bool WRITE_HNEW>
__global__ __launch_bounds__(256) void fgru(
    const __bf16* __restrict__ Ab, long long aBatch,     // (z, Mtot, HD) bf16
    const __bf16* __restrict__ Whh, long long wBatch,    // (z, 3HD, HD) bf16
    const float* __restrict__ bhh, long long bhhBatch,   // (z, 3HD)
    const float* __restrict__ gx, long long gxBatch,     // (z, Mtot, 3HD) fp32
    const float* __restrict__ hprev, long long hBatch,   // (z, ..., HD) fp32
    float* __restrict__ hout, long long hoBatch,         // fp32
    __bf16* __restrict__ hnew, long long hnBatch)        // bf16
{
    __shared__ __align__(16) __bf16 As[128 * 32];
    __shared__ __align__(16) __bf16 Bs[192 * 32];

    const int tid  = threadIdx.x;
    const int w    = tid >> 6;
    const int lane = tid & 63;
    const int m0 = blockIdx.x * 128;
    const int j0 = blockIdx.y * 64;
    const int z  = blockIdx.z;

    const int lrow = lane >> 2;
    const int lseg = lane & 3;
    const __bf16* Ag0 = Ab + (size_t)z * aBatch + (size_t)(m0 + w * 32 + lrow) * HD + lseg * 8;
    const __bf16* Ag1 = Ag0 + (size_t)16 * HD;
    __bf16* Al0 = As + (w * 32) * 32;
    __bf16* Al1 = Al0 + 16 * 32;

    // B: 192 rows = [r-gate 64 | z-gate 64 | n-gate 64] for cols j0..j0+63
    const __bf16* Wz = Whh + (size_t)z * wBatch;
    const __bf16* Bg[3];
    __bf16* Bl[3];
#pragma unroll
    for (int i = 0; i < 3; ++i) {
        const int r = (w * 3 + i) * 16 + lrow;          // 0..191
        const int gate = r >> 6;
        const int grow = gate * HD + j0 + (r & 63);
        Bg[i] = Wz + (size_t)grow * HD + lseg * 8;
        Bl[i] = Bs + ((w * 3 + i) * 16) * 32;
    }

    const int mh = w & 1, nh = w >> 1;
    const int lr16 = lane & 15;
    const int lq   = lane >> 4;
    const __bf16* Af = As + (mh * 64 + lr16) * 32 + lq * 8;
    const __bf16* Bf = Bs + (nh * 32 + lr16) * 32 + lq * 8;

    floatx4 acc[3][4][2];
#pragma unroll
    for (int g = 0; g < 3; ++g)
#pragma unroll
        for (int i = 0; i < 4; ++i)
#pragma unroll
            for (int j = 0; j < 2; ++j) acc[g][i][j] = (floatx4){0.f, 0.f, 0.f, 0.f};

    for (int k0 = 0; k0 < HD; k0 += 32) {
        __syncthreads();
        load_lds16(Ag0 + k0, Al0);
        load_lds16(Ag1 + k0, Al1);
#pragma unroll
        for (int i = 0; i < 3; ++i) load_lds16(Bg[i] + k0, Bl[i]);
        __syncthreads();

        bf16x8 af[4], bf[3][2];
#pragma unroll
        for (int t = 0; t < 4; ++t) af[t] = *(const bf16x8*)(Af + t * 16 * 32);
#pragma unroll
        for (int g = 0; g < 3; ++g)
#pragma unroll
            for (int tn = 0; tn < 2; ++tn)
                bf[g][tn] = *(const bf16x8*)(Bf + (g * 64 + tn * 16) * 32);
#pragma unroll
        for (int g = 0; g < 3; ++g)
#pragma unroll
            for (int tm = 0; tm < 4; ++tm)
#pragma unroll
                for (int tn = 0; tn < 2; ++tn)
                    acc[g][tm][tn] = __builtin_amdgcn_mfma_f32_16x16x32_bf16(af[tm], bf[g][tn], acc[g][tm][tn], 0, 0, 0);
    }

    const float* bhhz = bhh + (size_t)z * bhhBatch;
#pragma unroll
    for (int tm = 0; tm < 4; ++tm) {
#pragma unroll
        for (int rr = 0; rr < 4; ++rr) {
            const int row = m0 + mh * 64 + tm * 16 + lq * 4 + rr;
            const float* gxrow = gx + (size_t)z * gxBatch + (size_t)row * (3 * HD);
            const float* hrow  = hprev + (size_t)z * hBatch + (size_t)row * HD;
#pragma unroll
            for (int tn = 0; tn < 2; ++tn) {
                const int j = j0 + nh * 32 + tn * 16 + lr16;
                float ghr = acc[0][tm][tn][rr] + bhhz[j];
                float ghz = acc[1][tm][tn][rr] + bhhz[HD + j];
                float ghn = acc[2][tm][tn][rr] + bhhz[2 * HD + j];
                float r  = sigmoidf_(gxrow[j] + ghr);
                float zz = sigmoidf_(gxrow[HD + j] + ghz);
                float n  = tanhf(gxrow[2 * HD + j] + r * ghn);
                float hv = hrow[j];
                float o  = (1.f - zz) * n + zz * hv;
                hout[(size_t)z * hoBatch + (size_t)row * HD + j] = o;
                if (WRITE_HNEW)
                    hnew[(size_t)z * hnBatch + (size_t)row * HD + j] = (__bf16)o;
            }
        }
    }
}

// ---------------- router fc + softmax ----------------
__global__ __launch_bounds__(256) void fc_softmax_k(const float* __restrict__ hr,
                                                    const float* __restrict__ Wfc,
                                                    const float* __restrict__ bfc,
                                                    float* __restrict__ wts) {
    int lane = threadIdx.x & 63;
    int wave = threadIdx.x >> 6;
    int rg = lane >> 3;
    int e  = lane & 7;
    int b  = blockIdx.x * 32 + wave * 8 + rg;
    const float* h = hr + (size_t)b * HR_;
    const float* w = Wfc + (size_t)e * HR_;
    float acc = 0.0f;
#pragma unroll 4
    for (int k = 0; k < HR_; k += 4) {
        float4 hv = *(const float4*)(h + k);
        float4 wv = *(const float4*)(w + k);
        acc += hv.x * wv.x + hv.y * wv.y + hv.z * wv.z + hv.w * wv.w;
    }
    acc += bfc[e];
    float m = acc;
    for (int off = 4; off; off >>= 1) m = fmaxf(m, __shfl_xor(m, off, 8));
    float ex = __expf(acc - m);
    float s = ex;
    for (int off = 4; off; off >>= 1) s += __shfl_xor(s, off, 8);
    wts[(size_t)b * E_ + e] = ex / s;
}

// ---------------- reduce 8 expert P planes (chunk) -> comb ----------------
__global__ __launch_bounds__(256) void reduce8_k(const float* __restrict__ P,
                                                 float* __restrict__ comb, int n4) {
    int i = blockIdx.x * 256 + threadIdx.x;   // over 1024*512/4
    if (i >= n4) return;
    const size_t ps = (size_t)1024 * 512 / 4;
    float4 s = ((const float4*)P)[i];
#pragma unroll
    for (int e = 1; e < E_; ++e) {
        float4 v = ((const float4*)P)[i + (size_t)e * ps];
        s.x += v.x; s.y += v.y; s.z += v.z; s.w += v.w;
    }
    ((float4*)comb)[i] = s;
}

// ---------------- head ----------------
__global__ __launch_bounds__(256) void head_k(const float* __restrict__ comb,
                                              const float* __restrict__ Wh,
                                              const float* __restrict__ bh,
                                              float* __restrict__ out) {
    __shared__ float hs[8][512];
    int b0 = blockIdx.x * 8;
    for (int i = threadIdx.x; i < 8 * 128; i += 256) {
        int rr = i >> 7, cc = i & 127;
        ((float4*)hs[rr])[cc] = ((const float4*)(comb + (size_t)(b0 + rr) * 512))[cc];
    }
    __syncthreads();
    int r = threadIdx.x >> 5, c = threadIdx.x & 31;
    const float* wrow = Wh + (size_t)c * 512;
    float acc = 0.f;
    for (int k = 0; k < 512; k += 4) {
        float4 wv = *(const float4*)(wrow + k);
        float4 hv = *(const float4*)(&hs[r][k]);
        acc += hv.x * wv.x + hv.y * wv.y + hv.z * wv.z + hv.w * wv.w;
    }
    out[(size_t)(b0 + r) * 32 + c] = acc + bh[c];
}

// ---------------- launcher ----------------
extern "C" void kernel_launch(void* const* d_in, const int* in_sizes, int n_in,
                              void* d_out, int out_size, void* d_ws, size_t ws_size,
                              hipStream_t stream)
{
    const float* x      = (const float*)d_in[0];
    const float* lang   = (const float*)d_in[1];
    const float* h_r    = (const float*)d_in[2];
    const float* h_e    = (const float*)d_in[3];
    const float* W_in   = (const float*)d_in[4];
    const float* b_in   = (const float*)d_in[5];
    const float* Wih_r  = (const float*)d_in[6];
    const float* Whh_r  = (const float*)d_in[7];
    const float* bih_r  = (const float*)d_in[8];
    const float* bhh_r  = (const float*)d_in[9];
    const float* W_fc   = (const float*)d_in[10];
    const float* b_fc   = (const float*)d_in[11];
    const float* Wih_e  = (const float*)d_in[12];
    const float* Whh_e  = (const float*)d_in[13];
    const float* bih_e  = (const float*)d_in[14];
    const float* bhh_e  = (const float*)d_in[15];
    const float* W_proj = (const float*)d_in[16];
    const float* b_proj = (const float*)d_in[17];
    const float* W_head = (const float*)d_in[18];
    const float* b_head = (const float*)d_in[19];

    float* out_logits = (float*)d_out;                 // B*A
    float* out_hr     = out_logits + (size_t)B_ * A_;  // B*HR
    float* out_he     = out_hr + (size_t)B_ * HR_;     // E*B*H

    char* wsb = (char*)d_ws;
    size_t off = 0;
    auto alloc = [&](size_t bytes) -> char* {
        char* p = wsb + off;
        off = (off + bytes + 255) & ~(size_t)255;
        return p;
    };

    // ---- persistent (through expert loop): 63.0 MB ----
    __bf16* Wih_e_hl = (__bf16*)alloc((size_t)12288 * 1024 * 2);   // [hi|lo]
    __bf16* Whh_e_b  = (__bf16*)alloc((size_t)8 * 1536 * 512 * 2);
    __bf16* W_proj_b = (__bf16*)alloc((size_t)8 * 512 * 512 * 2);
    __bf16* xp_cat   = (__bf16*)alloc((size_t)B_ * 1536 * 2);      // [hi|hi|lo]
    float*  wts      = (float*)alloc((size_t)B_ * E_ * 4);
    float*  comb     = (float*)alloc((size_t)B_ * D_ * 4);

    // ---- region R: max(prep ~42 MB, chunk 67.1 MB) ----
    char* R = wsb + off;
    // prep-phase layout within R:
    __bf16* W_in_hl  = (__bf16*)(R);                                   // 512*1280*2  = 1.31 MB
    __bf16* Wih_r_hl = (__bf16*)(R + 1310720);                         // 768*1024*2  = 1.57 MB
    __bf16* Whh_r_b  = (__bf16*)(R + 1310720 + 1572864);               // 768*256*2   = 0.39 MB
    __bf16* hr_b     = (__bf16*)(R + 1310720 + 1572864 + 393216);      // B*256*2     = 2.10 MB
    char*   Rp       = R + 1310720 + 1572864 + 393216 + 2097152;
    __bf16* xcat_cat = (__bf16*)(Rp);                                  // B*1920*2    = 15.73 MB
    float*  xp       = (float*)(Rp + 15728640);                        // B*512*4     = 8.39 MB
    float*  gxr      = (float*)(Rp + 15728640 + 8388608);              // B*768*4     = 12.58 MB
    // chunk-phase layout within R (prep all dead by then):
    float*  gxch     = (float*)(R);                                    // 8*1024*1536*4 = 50.33 MB
    float*  Pch      = (float*)(R);                                    // 8*1024*512*4 = 16.8 MB (reuses gxch)
    __bf16* hebch    = (__bf16*)(R + 50331648);                        // 8*1024*512*2 = 8.39 MB
    __bf16* henewch  = (__bf16*)(R + 50331648 + 8388608);              // 8.39 MB
    // total footprint: 63.0 + 67.1 = 130.2 MB

    // ---- weight prep ----
    wcat2_k<<<(512 * 160 + 255) / 256, 256, 0, stream>>>(W_in, W_in_hl, 160, 512 * 160);
    wcat2_k<<<(768 * 128 + 255) / 256, 256, 0, stream>>>(Wih_r, Wih_r_hl, 128, 768 * 128);
    wcat2_k<<<(12288 * 128 + 255) / 256, 256, 0, stream>>>(Wih_e, Wih_e_hl, 128, 12288 * 128);
    f2b_k<<<(49152 + 255) / 256, 256, 0, stream>>>(Whh_r, Whh_r_b, 49152);
    f2b_k<<<(1572864 + 255) / 256, 256, 0, stream>>>(Whh_e, Whh_e_b, 1572864);
    f2b_k<<<(524288 + 255) / 256, 256, 0, stream>>>(W_proj, W_proj_b, 524288);
    f2b_k<<<(262144 + 255) / 256, 256, 0, stream>>>(h_r, hr_b, 262144);

    // ---- input projection (hi/lo accurate) ----
    concat_cat_k<<<(B_ * 160) / 256, 256, 0, stream>>>(x, lang, xcat_cat);
    mgemm<0><<<dim3(32, 4, 1), 256, 0, stream>>>(xcat_cat, 0, W_in_hl, 0, 1280, 1280,
                                                 b_in, 0, xp, 0, D_, 1920, nullptr, 0, 0);
    split2cat_k<<<(B_ * 128) / 256, 256, 0, stream>>>(xp, xp_cat);

    // ---- router: gx GEMM, fused gh+GRU, softmax ----
    mgemm<0><<<dim3(32, 6, 1), 256, 0, stream>>>(xp_cat, 0, Wih_r_hl, 0, 1024, 1024,
                                                 bih_r, 0, gxr, 0, 3 * HR_, 1536, nullptr, 0, 0);
    fgru<HR_, false><<<dim3(32, 4, 1), 256, 0, stream>>>(
        hr_b, 0, Whh_r_b, 0, bhh_r, 0, gxr, 0, h_r, 0, out_hr, 0, nullptr, 0);
    fc_softmax_k<<<B_ / 32, 256, 0, stream>>>(out_hr, W_fc, b_fc, wts);

    // ---- experts: 4 row-chunks of 1024, all 8 experts batched in z ----
    for (int c = 0; c < 4; ++c) {
        const int r0 = c * 1024;
        f2bhe_k<<<(8 * 1024 * 128) / 256, 256, 0, stream>>>(h_e, hebch, r0);
        // gx (hi/lo accurate): (1024 x 1536) per expert
        mgemm<0><<<dim3(8, 12, 8), 256, 0, stream>>>(
            xp_cat + (size_t)r0 * 1536, 0,
            Wih_e_hl, (long long)1536 * 1024, 1024, 1024,
            bih_e, 3 * H_,
            gxch, (long long)1024 * 3 * H_, 3 * H_, 1536, nullptr, 0, 0);
        // fused gh-GEMM + GRU -> out_he (fp32) + henew (bf16)
        fgru<H_, true><<<dim3(8, 8, 8), 256, 0, stream>>>(
            hebch, (long long)1024 * H_,
            Whh_e_b, (long long)3 * H_ * H_,
            bhh_e, 3 * H_,
            gxch, (long long)1024 * 3 * H_,
            h_e + (size_t)r0 * H_, (long long)B_ * H_,
            out_he + (size_t)r0 * H_, (long long)B_ * H_,
            henewch, (long long)1024 * H_);
        // weighted projection into P planes (gxch now dead; P reuses it)
        mgemm<2><<<dim3(8, 4, 8), 256, 0, stream>>>(
            henewch, (long long)1024 * H_,
            W_proj_b, (long long)D_ * H_, 512, 512,
            b_proj, D_,
            Pch, (long long)1024 * D_, D_, H_,
            wts + (size_t)r0 * E_, E_, 1);
        reduce8_k<<<(1024 * 128 + 255) / 256, 256, 0, stream>>>(
            Pch, comb + (size_t)r0 * D_, 1024 * 128);
    }

    // ---- head ----
    head_k<<<B_ / 8, 256, 0, stream>>>(comb, W_head, b_head, out_logits);
}